// Round 2
// baseline (601.541 us; speedup 1.0000x reference)
//
#include <hip/hip_runtime.h>
#include <stdint.h>

// ---------- vector types / helpers ----------
typedef __attribute__((ext_vector_type(8))) short bf16x8;
typedef __attribute__((ext_vector_type(4))) float f32x4;
typedef __attribute__((ext_vector_type(4))) unsigned short u16x4;
typedef __attribute__((ext_vector_type(8))) unsigned short u16x8;

__device__ __forceinline__ unsigned short f2bf(float f) {
  unsigned int u = __builtin_bit_cast(unsigned int, f);
  u = (u + 0x7fffu + ((u >> 16) & 1u)) >> 16;  // RNE
  return (unsigned short)u;
}
__device__ __forceinline__ float bf2f(unsigned short s) {
  unsigned int u = ((unsigned int)s) << 16;
  return __builtin_bit_cast(float, u);
}

// async global->LDS, 16B per lane (guide: m97 pattern; LDS dest must be linear)
__device__ __forceinline__ void g2lds16(const void* g, void* l) {
  __builtin_amdgcn_global_load_lds((const __attribute__((address_space(1))) void*)g,
                                   (__attribute__((address_space(3))) void*)l,
                                   16, 0, 0);
}

// ---------- cast fp32 -> bf16 (z selects source/dest pair) ----------
__global__ __launch_bounds__(256) void cast_f32_bf16(const float* __restrict__ in0,
                                                     unsigned short* __restrict__ out0,
                                                     const float* __restrict__ in1,
                                                     unsigned short* __restrict__ out1,
                                                     int n4) {
  const float* in = blockIdx.z ? in1 : in0;
  unsigned short* out = blockIdx.z ? out1 : out0;
  int i = blockIdx.x * 256 + threadIdx.x;
  const int stride = gridDim.x * 256;
  for (; i < n4; i += stride) {
    float4 v = reinterpret_cast<const float4*>(in)[i];
    u16x4 o;
    o.x = f2bf(v.x); o.y = f2bf(v.y); o.z = f2bf(v.z); o.w = f2bf(v.w);
    reinterpret_cast<u16x4*>(out)[i] = o;
  }
}

// ---------- transpose + cast weights: T[n][k] = W[k][n], 1024x1024 ----------
__global__ __launch_bounds__(256) void transpose_cast_w(
    const float* __restrict__ W0, const float* __restrict__ W1, const float* __restrict__ W2,
    unsigned short* __restrict__ T0, unsigned short* __restrict__ T1, unsigned short* __restrict__ T2) {
  const float* W = blockIdx.z == 0 ? W0 : (blockIdx.z == 1 ? W1 : W2);
  unsigned short* T = blockIdx.z == 0 ? T0 : (blockIdx.z == 1 ? T1 : T2);
  __shared__ unsigned short tile[32][33];
  const int tx = threadIdx.x & 31, ty = threadIdx.x >> 5;
  const int r0 = blockIdx.y * 32, c0 = blockIdx.x * 32;
#pragma unroll
  for (int i = 0; i < 4; i++) {
    int r = ty + i * 8;
    tile[r][tx] = f2bf(W[(size_t)(r0 + r) * 1024 + c0 + tx]);
  }
  __syncthreads();
#pragma unroll
  for (int i = 0; i < 4; i++) {
    int r = ty + i * 8;
    T[(size_t)(c0 + r) * 1024 + r0 + tx] = tile[tx][r];
  }
}

// ---------- m97-structure GEMM: C[m][n] = sum_k A[m][k] * Bt[n][k] ----------
// 128x128 tile, BK=32, 4 waves (2x2 of 64x64), global_load_lds w=16,
// mfma_f32_16x16x32_bf16, acc 4x4 f32x4.
// MODE 0: bf16 out + per-col bias | 1: bf16 out + per-row bias
// MODE 2: bf16 out, *scale then clip +-100 | 3: fp32 out
template <int MODE>
__global__ __launch_bounds__(256) void gemm_bt(
    const unsigned short* __restrict__ Aall, const unsigned short* __restrict__ Btall,
    const float* __restrict__ bias, void* __restrict__ Call,
    int M, int N, int K, long long sA, long long sB, long long sC, float scale) {
  __shared__ unsigned short As[128 * 32];
  __shared__ unsigned short Bs[128 * 32];

  const unsigned short* A = Aall + (size_t)blockIdx.z * sA;
  const unsigned short* Bt = Btall + (size_t)blockIdx.z * sB;

  const int tid = threadIdx.x;
  const int lane = tid & 63;
  const int w = tid >> 6;
  const int wr = w >> 1, wc = w & 1;           // 2x2 wave grid, 64x64 each
  const int lane16 = lane & 15, kg = lane >> 4;
  const int m0 = blockIdx.y * 128, n0 = blockIdx.x * 128;

  // staging: 128x32 bf16 tile = 8KB; 256 thr x 16B x 2 rounds per matrix
  const int e0 = tid * 8;                      // elem index, round 0
  const int ra = e0 >> 5, ca = e0 & 31;
  const unsigned short* gA = A + (size_t)(m0 + ra) * K + ca;
  const unsigned short* gB = Bt + (size_t)(n0 + ra) * K + ca;
  unsigned short* lA0 = &As[e0];
  unsigned short* lA1 = &As[e0 + 2048];
  unsigned short* lB0 = &Bs[e0];
  unsigned short* lB1 = &Bs[e0 + 2048];
  const size_t rstep = (size_t)64 * K;         // +64 rows for round 1

  const int aoff = (wr * 64 + lane16) * 32 + kg * 8;
  const int boff = (wc * 64 + lane16) * 32 + kg * 8;

  f32x4 acc[4][4] = {};

  for (int k0 = 0; k0 < K; k0 += 32) {
    g2lds16(gA + k0, lA0);
    g2lds16(gA + k0 + rstep, lA1);
    g2lds16(gB + k0, lB0);
    g2lds16(gB + k0 + rstep, lB1);
    __syncthreads();  // compiler inserts vmcnt(0) drain before s_barrier (m97)
    bf16x8 af[4], bfr[4];
#pragma unroll
    for (int m = 0; m < 4; m++)
      af[m] = *reinterpret_cast<const bf16x8*>(&As[aoff + m * 16 * 32]);
#pragma unroll
    for (int n = 0; n < 4; n++)
      bfr[n] = *reinterpret_cast<const bf16x8*>(&Bs[boff + n * 16 * 32]);
#pragma unroll
    for (int m = 0; m < 4; m++)
#pragma unroll
      for (int n = 0; n < 4; n++)
        acc[m][n] = __builtin_amdgcn_mfma_f32_16x16x32_bf16(af[m], bfr[n], acc[m][n], 0, 0, 0);
    __syncthreads();
  }

  // C/D layout: col = lane&15, row = (lane>>4)*4 + reg  [m89-verified]
  const int rbase = m0 + wr * 64 + kg * 4;
  const int cbase = n0 + wc * 64 + lane16;

  if constexpr (MODE == 3) {
    float* C = reinterpret_cast<float*>(Call) + (size_t)blockIdx.z * sC;
#pragma unroll
    for (int m = 0; m < 4; m++)
#pragma unroll
      for (int j = 0; j < 4; j++) {
        size_t r = (size_t)(rbase + m * 16 + j);
#pragma unroll
        for (int n = 0; n < 4; n++)
          C[r * N + cbase + n * 16] = acc[m][n][j];
      }
  } else {
    unsigned short* C = reinterpret_cast<unsigned short*>(Call) + (size_t)blockIdx.z * sC;
    float cb[4] = {0.f, 0.f, 0.f, 0.f};
    if constexpr (MODE == 0) {
#pragma unroll
      for (int n = 0; n < 4; n++) cb[n] = bias[cbase + n * 16];
    }
#pragma unroll
    for (int m = 0; m < 4; m++)
#pragma unroll
      for (int j = 0; j < 4; j++) {
        int r = rbase + m * 16 + j;
        float rb = 0.0f;
        if constexpr (MODE == 1) rb = bias[r];
#pragma unroll
        for (int n = 0; n < 4; n++) {
          float v = acc[m][n][j];
          if constexpr (MODE == 0) v += cb[n];
          if constexpr (MODE == 1) v += rb;
          if constexpr (MODE == 2) {
            v *= scale;
            v = fminf(fmaxf(v, -100.0f), 100.0f);
          }
          C[(size_t)r * N + cbase + n * 16] = f2bf(v);
        }
      }
  }
}

// ---------- in-place row softmax over [rows][2048] bf16 ----------
__global__ __launch_bounds__(256) void softmax_rows(unsigned short* __restrict__ S) {
  const size_t row = blockIdx.x;
  unsigned short* p = S + row * 2048;
  const int tid = threadIdx.x;
  const int lane = tid & 63, wv = tid >> 6;

  u16x8 raw = *reinterpret_cast<const u16x8*>(&p[tid * 8]);
  float v[8];
#pragma unroll
  for (int i = 0; i < 8; i++) v[i] = bf2f(raw[i]);

  float m = v[0];
#pragma unroll
  for (int i = 1; i < 8; i++) m = fmaxf(m, v[i]);
#pragma unroll
  for (int off = 32; off > 0; off >>= 1) m = fmaxf(m, __shfl_xor(m, off));

  __shared__ float red[8];
  if (lane == 0) red[wv] = m;
  __syncthreads();
  m = fmaxf(fmaxf(red[0], red[1]), fmaxf(red[2], red[3]));

  float e[8];
  float s = 0.f;
#pragma unroll
  for (int i = 0; i < 8; i++) { e[i] = __expf(v[i] - m); s += e[i]; }
#pragma unroll
  for (int off = 32; off > 0; off >>= 1) s += __shfl_xor(s, off);
  if (lane == 0) red[4 + wv] = s;
  __syncthreads();
  s = red[4] + red[5] + red[6] + red[7];
  const float inv = 1.0f / s;

  u16x8 o;
#pragma unroll
  for (int i = 0; i < 8; i++) o[i] = f2bf(e[i] * inv);
  *reinterpret_cast<u16x8*>(&p[tid * 8]) = o;
}

// ---------- launch ----------
extern "C" void kernel_launch(void* const* d_in, const int* in_sizes, int n_in,
                              void* d_out, int out_size, void* d_ws, size_t ws_size,
                              hipStream_t stream) {
  const float* X1 = (const float*)d_in[0];
  const float* X2 = (const float*)d_in[1];
  const float* Wq = (const float*)d_in[2];
  const float* bq = (const float*)d_in[3];
  const float* Wk = (const float*)d_in[4];
  const float* bk = (const float*)d_in[5];
  const float* Wv = (const float*)d_in[6];
  const float* bv = (const float*)d_in[7];

  char* ws = (char*)d_ws;
  const size_t MB = 1024 * 1024;
  // ws layout (102 MiB total):
  //   [0,32M)   X1b bf16           -- dead after Q gemm
  //   [32,64M)  X2b bf16           -- dead after V gemm
  //   [0,64M)   Sbuf bf16 (scores/weights) -- written after X1b/X2b dead
  //   [64,70M)  Wqt/Wkt/Wvt bf16
  //   [70,102M) Vt bf16 [8][1024][2048]
  // d_out doubles as scratch for Qb/Kb bf16 (dead before PV overwrites).
  unsigned short* X1b = (unsigned short*)(ws);
  unsigned short* X2b = (unsigned short*)(ws + 32 * MB);
  unsigned short* Sbuf = (unsigned short*)(ws);
  unsigned short* Wqt = (unsigned short*)(ws + 64 * MB);
  unsigned short* Wkt = (unsigned short*)(ws + 66 * MB);
  unsigned short* Wvt = (unsigned short*)(ws + 68 * MB);
  unsigned short* Vt = (unsigned short*)(ws + 70 * MB);
  unsigned short* Qb = (unsigned short*)d_out;
  unsigned short* Kb = Qb + 16777216;
  float* out = (float*)d_out;

  // 1) casts (one launch, z selects X1/X2)
  cast_f32_bf16<<<dim3(2048, 1, 2), 256, 0, stream>>>(X1, X1b, X2, X2b, 4194304);
  transpose_cast_w<<<dim3(32, 32, 3), 256, 0, stream>>>(Wq, Wk, Wv, Wqt, Wkt, Wvt);

  // 2) projections: Q = X1*Wq + bq ; K = X2*Wk + bk  (bf16 into d_out scratch)
  gemm_bt<0><<<dim3(8, 128, 1), 256, 0, stream>>>(X1b, Wqt, bq, Qb,
                                                  16384, 1024, 1024, 0, 0, 0, 1.0f);
  gemm_bt<0><<<dim3(8, 128, 1), 256, 0, stream>>>(X2b, Wkt, bk, Kb,
                                                  16384, 1024, 1024, 0, 0, 0, 1.0f);
  // Vt[b][d][l] = sum_k Wv[k][d]*X2[b][l][k] + bv[d]   (per-row bias = bv)
  gemm_bt<1><<<dim3(16, 8, 8), 256, 0, stream>>>(Wvt, X2b, bv, Vt,
                                                 1024, 2048, 1024,
                                                 0, (long long)2048 * 1024,
                                                 (long long)1024 * 2048, 1.0f);

  // 3) scores: S[b] = clip(Q[b]*K[b]^T / 32)  -> bf16 (aliases dead X1b/X2b)
  gemm_bt<2><<<dim3(16, 16, 8), 256, 0, stream>>>(Qb, Kb, nullptr, Sbuf,
                                                  2048, 2048, 1024,
                                                  (long long)2048 * 1024,
                                                  (long long)2048 * 1024,
                                                  (long long)2048 * 2048, 0.03125f);

  // 4) softmax rows (in place)
  softmax_rows<<<16384, 256, 0, stream>>>(Sbuf);

  // 5) out[b] = P[b] * V[b]  (Bt = Vt), fp32 into d_out (overwrites Qb/Kb)
  gemm_bt<3><<<dim3(8, 16, 8), 256, 0, stream>>>(Sbuf, Vt, nullptr, out,
                                                 2048, 1024, 2048,
                                                 (long long)2048 * 2048,
                                                 (long long)1024 * 2048,
                                                 (long long)2048 * 1024, 1.0f);
}

// Round 3
// 438.321 us; speedup vs baseline: 1.3724x; 1.3724x over previous
//
#include <hip/hip_runtime.h>
#include <stdint.h>

// ---------- vector types / helpers ----------
typedef __attribute__((ext_vector_type(8))) short bf16x8;
typedef __attribute__((ext_vector_type(4))) float f32x4;
typedef __attribute__((ext_vector_type(4))) unsigned short u16x4;
typedef __attribute__((ext_vector_type(8))) unsigned short u16x8;

__device__ __forceinline__ unsigned short f2bf(float f) {
  unsigned int u = __builtin_bit_cast(unsigned int, f);
  u = (u + 0x7fffu + ((u >> 16) & 1u)) >> 16;  // RNE
  return (unsigned short)u;
}
__device__ __forceinline__ float bf2f(unsigned short s) {
  unsigned int u = ((unsigned int)s) << 16;
  return __builtin_bit_cast(float, u);
}

__device__ __forceinline__ void g2lds16(const void* g, void* l) {
  __builtin_amdgcn_global_load_lds((const __attribute__((address_space(1))) void*)g,
                                   (__attribute__((address_space(3))) void*)l,
                                   16, 0, 0);
}

// ---------- cast fp32 -> bf16 (z selects source/dest pair) ----------
__global__ __launch_bounds__(256) void cast_f32_bf16(const float* __restrict__ in0,
                                                     unsigned short* __restrict__ out0,
                                                     const float* __restrict__ in1,
                                                     unsigned short* __restrict__ out1,
                                                     int n4) {
  const float* in = blockIdx.z ? in1 : in0;
  unsigned short* out = blockIdx.z ? out1 : out0;
  int i = blockIdx.x * 256 + threadIdx.x;
  const int stride = gridDim.x * 256;
  for (; i < n4; i += stride) {
    float4 v = reinterpret_cast<const float4*>(in)[i];
    u16x4 o;
    o.x = f2bf(v.x); o.y = f2bf(v.y); o.z = f2bf(v.z); o.w = f2bf(v.w);
    reinterpret_cast<u16x4*>(out)[i] = o;
  }
}

// ---------- transpose + cast weights: T[n][k] = W[k][n], 1024x1024 ----------
__global__ __launch_bounds__(256) void transpose_cast_w(
    const float* __restrict__ W0, const float* __restrict__ W1, const float* __restrict__ W2,
    unsigned short* __restrict__ T0, unsigned short* __restrict__ T1, unsigned short* __restrict__ T2) {
  const float* W = blockIdx.z == 0 ? W0 : (blockIdx.z == 1 ? W1 : W2);
  unsigned short* T = blockIdx.z == 0 ? T0 : (blockIdx.z == 1 ? T1 : T2);
  __shared__ unsigned short tile[32][33];
  const int tx = threadIdx.x & 31, ty = threadIdx.x >> 5;
  const int r0 = blockIdx.y * 32, c0 = blockIdx.x * 32;
#pragma unroll
  for (int i = 0; i < 4; i++) {
    int r = ty + i * 8;
    tile[r][tx] = f2bf(W[(size_t)(r0 + r) * 1024 + c0 + tx]);
  }
  __syncthreads();
#pragma unroll
  for (int i = 0; i < 4; i++) {
    int r = ty + i * 8;
    T[(size_t)(c0 + r) * 1024 + r0 + tx] = tile[tx][r];
  }
}

// ============ 256x256 8-phase GEMM (T1+T2+T3+T4+T5) ============
// C[m][n] = sum_k A[m][k]*Bt[n][k].  BM=BN=256, BK=64, 512 thr = 8 waves.
// Per phase: all 8 waves compute ONE 128x128 C-quadrant (mh,nh) -> each
// phase reads only A-half mh / B-half nh, freeing the other half for
// staging. LDS 2 dbuf x (A 32K + B 32K) = 128 KiB. Counted vmcnt(4) at
// phases 4/8 only. T2 XOR swizzle: physical_col_byte = logical ^ ((row&7)<<4),
// applied on BOTH the (per-lane) global staging source and the ds_read addr;
// LDS dest of global_load_lds stays linear (m104/m108/m173/rule 21).
// MODE 0: bf16 out + col bias | 1: bf16 out + row bias
// MODE 2: bf16 out, *scale, clip +-100 | 3: fp32 out
#define STAGE(buf, ab, h, kt)                                                          \
  {                                                                                    \
    const char* _s = ((ab) ? Bsrc : Asrc) + (size_t)(h) * 128 * K2 + (size_t)(kt) * 128; \
    char* _d = ldsb + (buf) * 65536 + (ab) * 32768 + (h) * 16384 + tid * 16;           \
    g2lds16(_s, _d);                                                                   \
    g2lds16(_s + 64 * K2, _d + 8192);                                                  \
  }
#define LOADA(buf, mh)                                                                 \
  _Pragma("unroll") for (int mf2 = 0; mf2 < 4; mf2++) {                                \
    const char* _p = ldsb + (buf) * 65536 + arow + ((mh) * 128 + mf2 * 16) * 128;      \
    aA[mf2][0] = *(const bf16x8*)(_p + colk0);                                         \
    aA[mf2][1] = *(const bf16x8*)(_p + colk1);                                         \
  }
#define LOADB(buf, nh)                                                                 \
  _Pragma("unroll") for (int nf2 = 0; nf2 < 2; nf2++) {                                \
    const char* _p = ldsb + (buf) * 65536 + 32768 + brow + ((nh) * 128 + nf2 * 16) * 128; \
    bB[nf2][0] = *(const bf16x8*)(_p + colk0);                                         \
    bB[nf2][1] = *(const bf16x8*)(_p + colk1);                                         \
  }
#define MFMAQ(mh, nh)                                                                  \
  __builtin_amdgcn_s_setprio(1);                                                       \
  _Pragma("unroll") for (int mf2 = 0; mf2 < 4; mf2++)                                  \
      _Pragma("unroll") for (int nf2 = 0; nf2 < 2; nf2++) {                            \
    acc[(mh)*4 + mf2][(nh)*2 + nf2] = __builtin_amdgcn_mfma_f32_16x16x32_bf16(         \
        aA[mf2][0], bB[nf2][0], acc[(mh)*4 + mf2][(nh)*2 + nf2], 0, 0, 0);             \
    acc[(mh)*4 + mf2][(nh)*2 + nf2] = __builtin_amdgcn_mfma_f32_16x16x32_bf16(         \
        aA[mf2][1], bB[nf2][1], acc[(mh)*4 + mf2][(nh)*2 + nf2], 0, 0, 0);             \
  }                                                                                    \
  __builtin_amdgcn_s_setprio(0);
#define BAR() __builtin_amdgcn_s_barrier()
#define VMW(n) asm volatile("s_waitcnt vmcnt(" #n ")" ::: "memory")

template <int MODE>
__global__ __launch_bounds__(512, 2) void gemm256(
    const unsigned short* __restrict__ Aall, const unsigned short* __restrict__ Btall,
    const float* __restrict__ bias, void* __restrict__ Call,
    int gm, int gn, int N, int K, long long sA, long long sB, long long sC, float scale) {
  __shared__ unsigned short lds[2][2][16384];  // [buf][A/B][256*64] = 128 KiB

  const int tid = threadIdx.x;
  const int lane = tid & 63;
  const int w = tid >> 6;
  const int wr = w >> 2, wc = w & 3;  // 2x4 waves within a 128x128 quadrant
  const int lane16 = lane & 15, kg = lane >> 4;

  // bijective XCD swizzle (gridDim.x % 8 == 0 guaranteed by launcher)
  const int q8 = gridDim.x >> 3;
  const int swz = (blockIdx.x & 7) * q8 + (blockIdx.x >> 3);
  const int z = swz / (gm * gn);
  const int r2 = swz % (gm * gn);
  const int m0 = (r2 / gn) * 256;
  const int n0 = (r2 % gn) * 256;

  const unsigned short* A = Aall + (size_t)z * sA;
  const unsigned short* Bt = Btall + (size_t)z * sB;
  const size_t K2 = (size_t)K * 2;

  // staging source (swizzle pre-applied to the per-lane global column)
  const int rowIn = tid >> 3;  // 0..63
  const int colSw = ((tid & 7) * 16) ^ ((rowIn & 7) << 4);
  const char* Asrc = (const char*)A + (size_t)(m0 + rowIn) * K2 + colSw;
  const char* Bsrc = (const char*)Bt + (size_t)(n0 + rowIn) * K2 + colSw;
  char* ldsb = (char*)&lds[0][0][0];

  // ds_read addressing (same XOR swizzle)
  const int colk0 = ((kg ^ (lane16 & 7)) << 4);
  const int colk1 = colk0 ^ 64;
  const int arow = (wr * 64 + lane16) * 128;  // byte row base within A half
  const int brow = (wc * 32 + lane16) * 128;  // byte row base within B half

  f32x4 acc[8][4] = {};
  bf16x8 aA[4][2], bB[2][2];

  const int nt = K >> 6;
  const int niter = nt >> 1;

  // prologue: tile0 (A0,B0,A1,B1) -> buf0 ; tile1 A0,B1 -> buf1
  STAGE(0, 0, 0, 0); STAGE(0, 1, 0, 0); STAGE(0, 0, 1, 0); STAGE(0, 1, 1, 0);
  STAGE(1, 0, 0, 1); STAGE(1, 1, 1, 1);
  VMW(4);  // tile0's 8 loads retired; tile1's 4 still in flight
  BAR();

  for (int i = 0; i < niter; i++) {
    const int t = 2 * i;
    const bool more = (i + 1 < niter);
    // ph1: quad(0,0) of tile t (buf0); stage A1 of t+1 -> buf1
    LOADA(0, 0); LOADB(0, 0);
    STAGE(1, 0, 1, t + 1);
    BAR(); MFMAQ(0, 0); BAR();
    // ph2: quad(0,1); stage B0 of t+1
    LOADB(0, 1);
    STAGE(1, 1, 0, t + 1);
    BAR(); MFMAQ(0, 1); BAR();
    // ph3: quad(1,1); stage A0 of t+2 (A0 of buf0 free since ph2 end)
    LOADA(0, 1);
    if (more) STAGE(0, 0, 0, t + 2);
    BAR(); MFMAQ(1, 1); BAR();
    // ph4: quad(1,0); stage B1 of t+2; counted wait covers t+1 halves
    LOADB(0, 0);
    if (more) { STAGE(0, 1, 1, t + 2); VMW(4); } else { VMW(0); }
    BAR(); MFMAQ(1, 0); BAR();
    // ph5: quad(0,0) of tile t+1 (buf1); stage A1 of t+2
    LOADA(1, 0); LOADB(1, 0);
    if (more) STAGE(0, 0, 1, t + 2);
    BAR(); MFMAQ(0, 0); BAR();
    // ph6: quad(0,1); stage B0 of t+2
    LOADB(1, 1);
    if (more) STAGE(0, 1, 0, t + 2);
    BAR(); MFMAQ(0, 1); BAR();
    // ph7: quad(1,1); stage A0 of t+3 -> buf1
    LOADA(1, 1);
    if (more) STAGE(1, 0, 0, t + 3);
    BAR(); MFMAQ(1, 1); BAR();
    // ph8: quad(1,0); stage B1 of t+3; counted wait covers t+2 fully
    LOADB(1, 0);
    if (more) { STAGE(1, 1, 1, t + 3); VMW(4); }
    BAR(); MFMAQ(1, 0); BAR();
  }

  // ---- epilogue ----
  // frag (a,b): row = m0 + (a>>2)*128 + wr*64 + (a&3)*16 + kg*4 + j
  //             col = n0 + (b>>1)*128 + wc*32 + (b&1)*16 + lane16
  const int rb0 = m0 + wr * 64 + kg * 4;
  const int cb0 = n0 + wc * 32 + lane16;
  if constexpr (MODE == 3) {
    float* C = (float*)Call + (size_t)z * sC;
#pragma unroll
    for (int a = 0; a < 8; a++)
#pragma unroll
      for (int j = 0; j < 4; j++) {
        size_t r = (size_t)(rb0 + (a >> 2) * 128 + (a & 3) * 16 + j);
#pragma unroll
        for (int b = 0; b < 4; b++)
          C[r * N + cb0 + (b >> 1) * 128 + (b & 1) * 16] = acc[a][b][j];
      }
  } else {
    unsigned short* C = (unsigned short*)Call + (size_t)z * sC;
    float cb[4] = {0.f, 0.f, 0.f, 0.f};
    if constexpr (MODE == 0) {
#pragma unroll
      for (int b = 0; b < 4; b++) cb[b] = bias[cb0 + (b >> 1) * 128 + (b & 1) * 16];
    }
#pragma unroll
    for (int a = 0; a < 8; a++)
#pragma unroll
      for (int j = 0; j < 4; j++) {
        int r = rb0 + (a >> 2) * 128 + (a & 3) * 16 + j;
        float rbias = 0.0f;
        if constexpr (MODE == 1) rbias = bias[r];
#pragma unroll
        for (int b = 0; b < 4; b++) {
          float v = acc[a][b][j];
          if constexpr (MODE == 0) v += cb[b];
          if constexpr (MODE == 1) v += rbias;
          if constexpr (MODE == 2) {
            v *= scale;
            v = fminf(fmaxf(v, -100.0f), 100.0f);
          }
          C[(size_t)r * N + cb0 + (b >> 1) * 128 + (b & 1) * 16] = f2bf(v);
        }
      }
  }
}

// ---------- in-place row softmax over [rows][2048] bf16 ----------
__global__ __launch_bounds__(256) void softmax_rows(unsigned short* __restrict__ S) {
  const size_t row = blockIdx.x;
  unsigned short* p = S + row * 2048;
  const int tid = threadIdx.x;
  const int lane = tid & 63, wv = tid >> 6;

  u16x8 raw = *reinterpret_cast<const u16x8*>(&p[tid * 8]);
  float v[8];
#pragma unroll
  for (int i = 0; i < 8; i++) v[i] = bf2f(raw[i]);

  float m = v[0];
#pragma unroll
  for (int i = 1; i < 8; i++) m = fmaxf(m, v[i]);
#pragma unroll
  for (int off = 32; off > 0; off >>= 1) m = fmaxf(m, __shfl_xor(m, off));

  __shared__ float red[8];
  if (lane == 0) red[wv] = m;
  __syncthreads();
  m = fmaxf(fmaxf(red[0], red[1]), fmaxf(red[2], red[3]));

  float e[8];
  float s = 0.f;
#pragma unroll
  for (int i = 0; i < 8; i++) { e[i] = __expf(v[i] - m); s += e[i]; }
#pragma unroll
  for (int off = 32; off > 0; off >>= 1) s += __shfl_xor(s, off);
  if (lane == 0) red[4 + wv] = s;
  __syncthreads();
  s = red[4] + red[5] + red[6] + red[7];
  const float inv = 1.0f / s;

  u16x8 o;
#pragma unroll
  for (int i = 0; i < 8; i++) o[i] = f2bf(e[i] * inv);
  *reinterpret_cast<u16x8*>(&p[tid * 8]) = o;
}

// ---------- launch ----------
extern "C" void kernel_launch(void* const* d_in, const int* in_sizes, int n_in,
                              void* d_out, int out_size, void* d_ws, size_t ws_size,
                              hipStream_t stream) {
  const float* X1 = (const float*)d_in[0];
  const float* X2 = (const float*)d_in[1];
  const float* Wq = (const float*)d_in[2];
  const float* bq = (const float*)d_in[3];
  const float* Wk = (const float*)d_in[4];
  const float* bk = (const float*)d_in[5];
  const float* Wv = (const float*)d_in[6];
  const float* bv = (const float*)d_in[7];

  char* ws = (char*)d_ws;
  const size_t MB = 1024 * 1024;
  // ws layout (102 MiB):  [0,32M) X1b | [32,64M) X2b | [0,64M) Sbuf (after
  // X1b/X2b dead) | [64,70M) Wqt/Wkt/Wvt | [70,102M) Vt.
  // d_out doubles as Qb/Kb bf16 scratch (dead before PV overwrites).
  unsigned short* X1b = (unsigned short*)(ws);
  unsigned short* X2b = (unsigned short*)(ws + 32 * MB);
  unsigned short* Sbuf = (unsigned short*)(ws);
  unsigned short* Wqt = (unsigned short*)(ws + 64 * MB);
  unsigned short* Wkt = (unsigned short*)(ws + 66 * MB);
  unsigned short* Wvt = (unsigned short*)(ws + 68 * MB);
  unsigned short* Vt = (unsigned short*)(ws + 70 * MB);
  unsigned short* Qb = (unsigned short*)d_out;
  unsigned short* Kb = Qb + 16777216;
  float* out = (float*)d_out;

  cast_f32_bf16<<<dim3(2048, 1, 2), 256, 0, stream>>>(X1, X1b, X2, X2b, 4194304);
  transpose_cast_w<<<dim3(32, 32, 3), 256, 0, stream>>>(Wq, Wk, Wv, Wqt, Wkt, Wvt);

  // Q = X1*Wq + bq : M=16384 (gm=64), N=1024 (gn=4) -> 256 blocks
  gemm256<0><<<dim3(256), 512, 0, stream>>>(X1b, Wqt, bq, Qb,
                                            64, 4, 1024, 1024, 0, 0, 0, 1.0f);
  gemm256<0><<<dim3(256), 512, 0, stream>>>(X2b, Wkt, bk, Kb,
                                            64, 4, 1024, 1024, 0, 0, 0, 1.0f);
  // Vt[b][d][l] = Wv^T X2^T + bv (row bias): M=1024 (gm=4), N=2048 (gn=8), z=8
  gemm256<1><<<dim3(256), 512, 0, stream>>>(Wvt, X2b, bv, Vt,
                                            4, 8, 2048, 1024,
                                            0, 2048LL * 1024, 1024LL * 2048, 1.0f);
  // scores: M=N=2048 (gm=gn=8), K=1024, z=8 -> 512 blocks
  gemm256<2><<<dim3(512), 512, 0, stream>>>(Qb, Kb, nullptr, Sbuf,
                                            8, 8, 2048, 1024,
                                            2048LL * 1024, 2048LL * 1024,
                                            2048LL * 2048, 0.03125f);
  softmax_rows<<<16384, 256, 0, stream>>>(Sbuf);
  // out = P*V : M=2048 (gm=8), N=1024 (gn=4), K=2048, z=8 -> 256 blocks
  gemm256<3><<<dim3(256), 512, 0, stream>>>(Sbuf, Vt, nullptr, out,
                                            8, 4, 1024, 2048,
                                            2048LL * 2048, 1024LL * 2048,
                                            2048LL * 1024, 1.0f);
}